// Round 1
// baseline (11181.647 us; speedup 1.0000x reference)
//
#include <hip/hip_runtime.h>
#include <hip/hip_cooperative_groups.h>

namespace cg = cooperative_groups;

#define NB    256
#define NT    512
#define BATCH 32
#define TENC  1024
#define HD    1024
#define ED    128
#define LL    128
#define GD    4096
#define IND   1152

// workspace layout (float offsets)
#define HBUF_OFF (BATCH*GD)                       // base: [0, BATCH*GD)
#define PART_OFF (HBUF_OFF + 3*BATCH*HD)          // h triple buffer
#define PSTRIDE  1028                             // acc[1024], m, s, pad
#define LG_OFF   (PART_OFF + 2*BATCH*32*PSTRIDE)  // logits double buffer

__device__ __forceinline__ float sigf(float x) {
  return __builtin_amdgcn_rcpf(1.0f + __expf(-x));
}
__device__ __forceinline__ float tanhf_fast(float x) {
  return 1.0f - 2.0f * __builtin_amdgcn_rcpf(1.0f + __expf(2.0f * x));
}
__device__ __forceinline__ float dot4(const float4& a, const float4& b) {
  return a.x*b.x + a.y*b.y + a.z*b.z + a.w*b.w;
}
__device__ __forceinline__ void fma4(float4& a, float p, const float4& c) {
  a.x = fmaf(p, c.x, a.x); a.y = fmaf(p, c.y, a.y);
  a.z = fmaf(p, c.z, a.z); a.w = fmaf(p, c.w, a.w);
}
__device__ __forceinline__ void mul4(float4& a, float s) { a.x*=s; a.y*=s; a.z*=s; a.w*=s; }

// base[b][g] = b_ih[g] + b_hh[g] + dot(ctx0[b], W_ih[g][E:E+H2])  (time-invariant)
__global__ __launch_bounds__(256) void base_kernel(
    const float* __restrict__ ctxt, const float* __restrict__ Wih,
    const float* __restrict__ bih, const float* __restrict__ bhh,
    float* __restrict__ base) {
  int id = blockIdx.x * 256 + threadIdx.x;
  int b = id & (BATCH - 1);
  int g = id >> 5;
  const float4* c4 = reinterpret_cast<const float4*>(ctxt + (size_t)b * TENC * HD);
  const float4* w4 = reinterpret_cast<const float4*>(Wih + (size_t)g * IND + ED);
  float a = bih[g] + bhh[g];
#pragma unroll 4
  for (int kk = 0; kk < HD/4; ++kk) {
    float4 cv = c4[kk];
    float4 wv = w4[kk];
    a += dot4(cv, wv);
  }
  base[(size_t)b * GD + g] = a;
}

// One persistent cooperative kernel; 1 grid sync per pipeline step.
// Pipeline at iteration k:
//   waves 0-3 : gates+cell(k)            -> h_k            (reads h_{k-1})
//   waves 4-7 : attn partials(k-1)       -> part[(k-1)&1]  (reads h_{k-1})
//               combine(k-2) -> LDS ctx; logits(k-2) -> lg[k&1]  (reads h_{k-2})
//   wave 7 of blk%8==0: log_softmax finalize(k-3) -> out
__global__ __launch_bounds__(NT, 2) void decoder_kernel(
    const float* __restrict__ ctxt, const float* __restrict__ gt,
    const float* __restrict__ Wih, const float* __restrict__ Whh,
    const float* __restrict__ Wout, const float* __restrict__ bout,
    float* __restrict__ ws, float* __restrict__ out) {
  cg::grid_group grid = cg::this_grid();
  const int blk = blockIdx.x;
  const int tid = threadIdx.x;
  const int lane = tid & 63;

  float* base  = ws;
  float* hbuf  = ws + HBUF_OFF;
  float* part  = ws + PART_OFF;
  float* lgbuf = ws + LG_OFF;

  __shared__ float ctx_lds[HD];

  // gates role mapping (tid < 256): wave w handles j = blk*4+w for all 32 b;
  // thread pair (half0,half1) covers rows (i,f) / (g,o) of unit (b,j).
  const int gu    = tid >> 1;
  const int ghalf = tid & 1;
  const int gb    = gu & (BATCH - 1);
  const int gj    = blk * 4 + (tid >> 6);
  const int gr0   = ghalf ? (2*HD + gj) : gj;
  const int gr1   = ghalf ? (3*HD + gj) : (HD + gj);
  float c_reg = 0.0f;   // LSTM cell state lives in registers (half0 threads)

  // attention role mapping (tid >= 256)
  const int ab     = blk >> 3;
  const int achunk = blk & 7;
  const int awv    = (tid >> 6) - 4;  // 0..3

  for (int k = 0; k <= 130; ++k) {
    const int hprev = (k + 2) % 3;   // h_{k-1}
    const int hcur  = k % 3;         // h_k
    const int hold  = (k + 1) % 3;   // h_{k-2}

    if (tid < 256) {
      if (k <= LL - 1) {
        const float4* h4  = reinterpret_cast<const float4*>(hbuf + (size_t)hprev*(BATCH*HD) + (size_t)gb*HD);
        const float4* w04 = reinterpret_cast<const float4*>(Whh + (size_t)gr0*HD);
        const float4* w14 = reinterpret_cast<const float4*>(Whh + (size_t)gr1*HD);
        float a0 = base[(size_t)gb*GD + gr0];
        float a1 = base[(size_t)gb*GD + gr1];
#pragma unroll 4
        for (int kk = 0; kk < HD/4; ++kk) {
          float4 hv = h4[kk];
          float4 wa = w04[kk];
          float4 wb = w14[kk];
          a0 += dot4(hv, wa);
          a1 += dot4(hv, wb);
        }
        if (k == 0) {
          // word_0 = onehot(0) -> just column 0 of W_ih
          a0 += Wih[(size_t)gr0 * IND];
          a1 += Wih[(size_t)gr1 * IND];
        } else {
          const float4* wd4 = reinterpret_cast<const float4*>(gt + ((size_t)gb*LL + (k-1))*ED);
          const float4* wi0 = reinterpret_cast<const float4*>(Wih + (size_t)gr0*IND);
          const float4* wi1 = reinterpret_cast<const float4*>(Wih + (size_t)gr1*IND);
#pragma unroll
          for (int kk = 0; kk < ED/4; ++kk) {
            float4 dv = wd4[kk];
            a0 += dot4(dv, wi0[kk]);
            a1 += dot4(dv, wi1[kk]);
          }
        }
        float p0 = __shfl_xor(a0, 1);
        float p1 = __shfl_xor(a1, 1);
        if (ghalf == 0) {
          // a0=i, a1=f, p0=g, p1=o
          float ig = sigf(a0);
          float fg = sigf(a1);
          float gg = tanhf_fast(p0);
          float og = sigf(p1);
          c_reg = fg * c_reg + ig * gg;
          hbuf[(size_t)hcur*(BATCH*HD) + (size_t)gb*HD + gj] = og * tanhf_fast(c_reg);
        }
      }
    } else {
      if (k >= 1 && k <= LL) {
        // flash-style single-pass online softmax over 32 positions per wave
        const float4* h4 = reinterpret_cast<const float4*>(hbuf + (size_t)hprev*(BATCH*HD) + (size_t)ab*HD);
        float4 hv0 = h4[lane], hv1 = h4[lane+64], hv2 = h4[lane+128], hv3 = h4[lane+192];
        float m = -INFINITY, s = 0.0f;
        float4 a0 = make_float4(0,0,0,0), a1 = a0, a2 = a0, a3 = a0;
        const float* cb = ctxt + (size_t)ab * TENC * HD;
        const int pos0 = achunk*128 + awv*32;
        const float4* cv4 = reinterpret_cast<const float4*>(cb + (size_t)pos0 * HD);
        float4 n0 = cv4[lane], n1 = cv4[lane+64], n2 = cv4[lane+128], n3 = cv4[lane+192];
        for (int i = 0; i < 32; ++i) {
          float4 c0 = n0, c1 = n1, c2 = n2, c3 = n3;
          if (i < 31) {  // prefetch next position (hide L3 latency)
            const float4* nx = reinterpret_cast<const float4*>(cb + (size_t)(pos0 + i + 1) * HD);
            n0 = nx[lane]; n1 = nx[lane+64]; n2 = nx[lane+128]; n3 = nx[lane+192];
          }
          float d = dot4(c0,hv0) + dot4(c1,hv1) + dot4(c2,hv2) + dot4(c3,hv3);
#pragma unroll
          for (int off = 32; off > 0; off >>= 1) d += __shfl_xor(d, off);
          float mn = fmaxf(m, d);
          if (mn > m) {      // wave-uniform branch
            float sc = __expf(m - mn);
            s *= sc;
            mul4(a0, sc); mul4(a1, sc); mul4(a2, sc); mul4(a3, sc);
            m = mn;
          }
          float p = __expf(d - m);
          s += p;
          fma4(a0, p, c0); fma4(a1, p, c1); fma4(a2, p, c2); fma4(a3, p, c3);
        }
        float* pb = part + ((((size_t)((k-1)&1))*BATCH + ab)*32 + (achunk*4 + awv))*PSTRIDE;
        *reinterpret_cast<float4*>(pb + 4*lane)       = a0;
        *reinterpret_cast<float4*>(pb + 256 + 4*lane) = a1;
        *reinterpret_cast<float4*>(pb + 512 + 4*lane) = a2;
        *reinterpret_cast<float4*>(pb + 768 + 4*lane) = a3;
        if (lane == 0) { pb[1024] = m; pb[1025] = s; }
      }
      if (k >= 2 && k <= LL + 1) {
        // combine 32 sub-chunk partials of (k-2) -> normalized ctx into LDS
        const float* pc = part + (((size_t)(k&1))*BATCH + ab)*32*PSTRIDE;
        float M = -INFINITY;
#pragma unroll
        for (int cc = 0; cc < 32; ++cc) M = fmaxf(M, pc[(size_t)cc*PSTRIDE + 1024]);
        const int k0 = awv*256 + 4*lane;
        float S = 0.0f;
        float4 cv = make_float4(0,0,0,0);
#pragma unroll 4
        for (int cc = 0; cc < 32; ++cc) {
          float w = __expf(pc[(size_t)cc*PSTRIDE + 1024] - M);
          S += w * pc[(size_t)cc*PSTRIDE + 1025];
          float4 av = *reinterpret_cast<const float4*>(pc + (size_t)cc*PSTRIDE + k0);
          fma4(cv, w, av);
        }
        float inv = __builtin_amdgcn_rcpf(S);
        ctx_lds[k0]   = cv.x * inv;
        ctx_lds[k0+1] = cv.y * inv;
        ctx_lds[k0+2] = cv.z * inv;
        ctx_lds[k0+3] = cv.w * inv;
      }
    }
    __syncthreads();
    if (tid >= 256 && k >= 2 && k <= LL + 1) {
      // logits(k-2): 16 output classes per block, 4 per wave
      const float4* hh4 = reinterpret_cast<const float4*>(hbuf + (size_t)hold*(BATCH*HD) + (size_t)ab*HD);
      const float4* cx4 = reinterpret_cast<const float4*>(ctx_lds);
#pragma unroll
      for (int q = 0; q < 4; ++q) {
        const int e = achunk*16 + awv*4 + q;
        const float4* woh = reinterpret_cast<const float4*>(Wout + (size_t)e * 2 * HD);
        const float4* woc = woh + HD/4;
        float d = 0.0f;
#pragma unroll
        for (int jj = 0; jj < 4; ++jj) {
          d += dot4(hh4[lane + 64*jj], woh[lane + 64*jj]);
          d += dot4(cx4[lane + 64*jj], woc[lane + 64*jj]);
        }
#pragma unroll
        for (int off = 32; off > 0; off >>= 1) d += __shfl_xor(d, off);
        if (lane == 0) lgbuf[((size_t)(k&1))*BATCH*ED + (size_t)ab*ED + e] = d + bout[e];
      }
    }
    if ((blk & 7) == 0 && tid >= 448 && k >= 3) {
      // log_softmax finalize for t = k-3
      const int t  = k - 3;
      const int fb = blk >> 3;
      const float* lg = lgbuf + ((size_t)((k-1)&1))*BATCH*ED + (size_t)fb*ED;
      const int l = tid - 448;
      float v0 = lg[l], v1 = lg[l+64];
      float mx = fmaxf(v0, v1);
#pragma unroll
      for (int off = 32; off > 0; off >>= 1) mx = fmaxf(mx, __shfl_xor(mx, off));
      float sm = __expf(v0 - mx) + __expf(v1 - mx);
#pragma unroll
      for (int off = 32; off > 0; off >>= 1) sm += __shfl_xor(sm, off);
      float lse = mx + __logf(sm);
      float* op = out + ((size_t)fb*LL + t)*ED;
      op[l]    = v0 - lse;
      op[l+64] = v1 - lse;
    }
    grid.sync();
  }
}

extern "C" void kernel_launch(void* const* d_in, const int* in_sizes, int n_in,
                              void* d_out, int out_size, void* d_ws, size_t ws_size,
                              hipStream_t stream) {
  (void)in_sizes; (void)n_in; (void)out_size; (void)ws_size;
  const float* ctxt = (const float*)d_in[0];
  const float* gt   = (const float*)d_in[1];
  const float* Wih  = (const float*)d_in[2];
  const float* Whh  = (const float*)d_in[3];
  const float* bih  = (const float*)d_in[4];
  const float* bhh  = (const float*)d_in[5];
  const float* Wout = (const float*)d_in[6];
  const float* bout = (const float*)d_in[7];
  float* out = (float*)d_out;
  float* ws  = (float*)d_ws;

  // zero h triple-buffer (h_{-1} = 0); cell state is register-held
  hipMemsetAsync(ws + HBUF_OFF, 0, (size_t)3*BATCH*HD*sizeof(float), stream);

  base_kernel<<<(BATCH*GD)/256, 256, 0, stream>>>(ctxt, Wih, bih, bhh, ws);

  void* args[] = { (void*)&ctxt, (void*)&gt, (void*)&Wih, (void*)&Whh,
                   (void*)&Wout, (void*)&bout, (void*)&ws, (void*)&out };
  hipLaunchCooperativeKernel((const void*)decoder_kernel, dim3(NB), dim3(NT),
                             args, 0, stream);
}